// Round 23
// baseline (17.407 us; speedup 1.0000x reference)
//
#include <hip/hip_runtime.h>

#define NS 8192
#define MS 2048
#define DD 32
#define MSPLIT 16
#define MCH 128       // m per block
#define NITS 8        // m-tiles per block
#define NT 2          // n-tiles per wave (R23: 4->2, grid.x 32->64, 4 blk/CU)
#define RBLK 32       // reduce blocks

typedef __attribute__((ext_vector_type(8))) short bf16x8;
typedef __attribute__((ext_vector_type(4))) float f32x4;
typedef unsigned short u16;
typedef unsigned int u32;

// ws byte offsets
#define PART_OFF 0                          // [MSPLIT][NS] f32 (512 KB)
#define MM_OFF   (MSPLIT * NS * 4)          // 2 u32 (min,max bits)
#define CNT_OFF  (MM_OFF + 8)               // 1 u32

__device__ inline float fast_exp2(float x) {
#if __has_builtin(__builtin_amdgcn_exp2f)
    return __builtin_amdgcn_exp2f(x);
#else
    return exp2f(x);
#endif
}
__device__ inline float fast_rcp(float x) {
#if __has_builtin(__builtin_amdgcn_rcpf)
    return __builtin_amdgcn_rcpf(x);
#else
    return 1.0f / x;
#endif
}

__device__ inline u32 cvt_pk_bf16(float a, float b) {
    u32 r;
    asm("v_cvt_pk_bf16_f32 %0, %1, %2" : "=v"(r) : "v"(a), "v"(b));
    return r;
}

// hi-only pack (W: lo term dropped in R22 — error budget 2.2e-8 vs 4.5e-8 thr)
__device__ inline bf16x8 pack8(const float* v) {
    union { u32 u[4]; bf16x8 b; } H;
#pragma unroll
    for (int j = 0; j < 4; ++j) H.u[j] = cvt_pk_bf16(v[2 * j], v[2 * j + 1]);
    return H.b;
}

// Split 8 floats into hi/lo bf16x8 (RNE) — used for X.
__device__ inline void split8(const float* v, bf16x8& hi, bf16x8& lo) {
    union { u32 u[4]; bf16x8 b; } H, L;
#pragma unroll
    for (int j = 0; j < 4; ++j) {
        u32 h = cvt_pk_bf16(v[2 * j], v[2 * j + 1]);
        float ha = __uint_as_float(h << 16);
        float hb = __uint_as_float(h & 0xFFFF0000u);
        L.u[j] = cvt_pk_bf16(v[2 * j] - ha, v[2 * j + 1] - hb);
        H.u[j] = h;
    }
    hi = H.b;
    lo = L.b;
}

// R22 body (16.85us) with per-wave n-tile halved: NT=2, grid.x=64 -> 1024
// blocks = 4 blocks/CU = 4 waves/SIMD (2x TLP vs R22's 2). R22's null result
// on the MFMA cut proved kde is latency-bound, not MFMA-bound; this buys
// latency hiding on the n-axis (X-conv total unchanged; W-conv total doubles,
// ~0.5us of cheap hi-only packs). Unlike R17, the conversion/load overlap
// structure is untouched — only the tile shrinks.
__global__ __launch_bounds__(256, 4) void kde_fused(const float* __restrict__ samples,
                                                    const float* __restrict__ means,
                                                    const float* __restrict__ stds,
                                                    unsigned char* __restrict__ wsb) {
    __shared__ u16 WBH[NITS * 512], WCH[NITS * 512];   // [it][qd][r15][8]
    __shared__ float A2s[MCH];

    const int t = threadIdx.x;
    const int m0 = blockIdx.y * MCH;
    const float L2E = 1.4426950408889634f;

    if (blockIdx.x == 0 && blockIdx.y == 0 && t == 0) {
        unsigned* mm = (unsigned*)(wsb + MM_OFF);
        mm[0] = 0x7f7fffffu;  // FLT_MAX bits (uint cmp == float cmp, all positive)
        mm[1] = 0u;
        *(unsigned*)(wsb + CNT_OFF) = 0u;
    }

    // ---- phase 1: W chunk -> LDS (hi only), one thread per (m_local, 16-d half) ----
    {
        const int ml = t >> 1, half = t & 1, d0 = half * 16;
        const float* mp = means + (size_t)(m0 + ml) * DD + d0;
        const float* vp = stds  + (size_t)(m0 + ml) * DD + d0;
        float mu[16], sd[16];
#pragma unroll
        for (int j = 0; j < 4; ++j) {
            float4 a4 = *(const float4*)(mp + j * 4);
            float4 c4 = *(const float4*)(vp + j * 4);
            mu[j*4+0]=a4.x; mu[j*4+1]=a4.y; mu[j*4+2]=a4.z; mu[j*4+3]=a4.w;
            sd[j*4+0]=c4.x; sd[j*4+1]=c4.y; sd[j*4+2]=c4.z; sd[j*4+3]=c4.w;
        }
        float Bv[16], Cv[16], a = 0.f;
#pragma unroll
        for (int j = 0; j < 16; ++j) {
            float inv = fast_rcp(sd[j]);
            Bv[j] = L2E * mu[j] * inv;
            Cv[j] = -0.5f * L2E * inv;
            a += mu[j] * mu[j] * inv;
        }
        a += __shfl_xor(a, 1);   // combine the two 16-d halves of row ml
        if (half == 0) A2s[ml] = -0.5f * L2E * a - 11.0f;  // -log2(M) folds mean

        const int it = ml >> 4, r15 = ml & 15;
#pragma unroll
        for (int r2 = 0; r2 < 2; ++r2) {
            const int qd = half * 2 + r2;
            const int base = ((it * 4 + qd) * 16 + r15) * 8;
            *(bf16x8*)&WBH[base] = pack8(Bv + r2 * 8);
            *(bf16x8*)&WCH[base] = pack8(Cv + r2 * 8);
        }
    }

    // ---- phase 2: X fragments straight from samples (both tiles up front) ----
    const int lane = t & 63, wid = t >> 6;
    const int r15 = lane & 15, g = lane >> 4;
    const int n0 = blockIdx.x * (NT * 16 * 4) + wid * (NT * 16);

    bf16x8 xh[NT], xl[NT], qh[NT], ql[NT];
#pragma unroll
    for (int nt = 0; nt < NT; ++nt) {
        const float* sp = samples + (size_t)(n0 + nt * 16 + r15) * DD + g * 8;
        float4 a4 = *(const float4*)sp, b4 = *(const float4*)(sp + 4);
        float xv[8] = {a4.x, a4.y, a4.z, a4.w, b4.x, b4.y, b4.z, b4.w};
        float qv[8];
#pragma unroll
        for (int j = 0; j < 8; ++j) qv[j] = xv[j] * xv[j];
        split8(xv, xh[nt], xl[nt]);
        split8(qv, qh[nt], ql[nt]);
    }

    __syncthreads();

    // ---- phase 3: m-loop, D = W·X (m on rows), 4 MFMAs per tile ----
    float rs[NT] = {0.f, 0.f};

#pragma unroll 2
    for (int it = 0; it < NITS; ++it) {
        const int base = ((it * 4 + g) * 16 + r15) * 8;
        bf16x8 bh = *(const bf16x8*)&WBH[base];
        bf16x8 ch = *(const bf16x8*)&WCH[base];
        // rows of this lane are m = it*16 + g*4 + r  ->  16B-aligned f32x4
        const f32x4 a2v = *(const f32x4*)&A2s[it * 16 + g * 4];
#pragma unroll
        for (int nt = 0; nt < NT; ++nt) {
            f32x4 acc = a2v;
            acc = __builtin_amdgcn_mfma_f32_16x16x32_bf16(bh, xh[nt], acc, 0, 0, 0);
            acc = __builtin_amdgcn_mfma_f32_16x16x32_bf16(ch, qh[nt], acc, 0, 0, 0);
            acc = __builtin_amdgcn_mfma_f32_16x16x32_bf16(bh, xl[nt], acc, 0, 0, 0);
            acc = __builtin_amdgcn_mfma_f32_16x16x32_bf16(ch, ql[nt], acc, 0, 0, 0);
            rs[nt] += (fast_exp2(acc[0]) + fast_exp2(acc[1]))
                    + (fast_exp2(acc[2]) + fast_exp2(acc[3]));
        }
    }

    // sum the 4 g-groups (m-row blocks): 2 shfl steps
#pragma unroll
    for (int nt = 0; nt < NT; ++nt) {
        rs[nt] += __shfl_xor(rs[nt], 16);
        rs[nt] += __shfl_xor(rs[nt], 32);
    }

    float* partial = (float*)(wsb + PART_OFF);
    if (g == 0) {   // lanes 0..15: n = n0 + nt*16 + r15, 64B coalesced per nt
#pragma unroll
        for (int nt = 0; nt < NT; ++nt)
            partial[(size_t)blockIdx.y * NS + n0 + nt * 16 + r15] = rs[nt];
    }
}

// Merged reduce+flip (R16, proven): 32 co-resident blocks; dist in registers;
// min/max atomics; counter rendezvous (cnt initialized by kde_fused, ordered
// by the kernel boundary); distributed flip.
__global__ __launch_bounds__(256) void reduce_flip(unsigned char* __restrict__ wsb,
                                                   float* __restrict__ out) {
    const float* partial = (const float*)(wsb + PART_OFF);
    unsigned* mm = (unsigned*)(wsb + MM_OFF);
    unsigned* cnt = (unsigned*)(wsb + CNT_OFF);

    const int tid = threadIdx.x;
    const int n = blockIdx.x * 256 + tid;
    float v = 0.f;
#pragma unroll
    for (int j = 0; j < MSPLIT; ++j) v += partial[(size_t)j * NS + n];

    float mn = v, mx = v;
#pragma unroll
    for (int o = 1; o < 64; o <<= 1) {
        mn = fminf(mn, __shfl_xor(mn, o));
        mx = fmaxf(mx, __shfl_xor(mx, o));
    }
    __shared__ float smn[4], smx[4];
    __shared__ float sres[2];
    const int wv = tid >> 6, ln = tid & 63;
    if (ln == 0) { smn[wv] = mn; smx[wv] = mx; }
    __syncthreads();
    if (tid == 0) {
#pragma unroll
        for (int j = 1; j < 4; ++j) {
            mn = fminf(mn, smn[j]);
            mx = fmaxf(mx, smx[j]);
        }
        atomicMin(mm + 0, __float_as_uint(mn));
        atomicMax(mm + 1, __float_as_uint(mx));
        __threadfence();                       // release our atomics
        atomicAdd(cnt, 1u);
        while (__hip_atomic_load(cnt, __ATOMIC_ACQUIRE, __HIP_MEMORY_SCOPE_AGENT)
               < RBLK) {}
        sres[0] = __uint_as_float(
            __hip_atomic_load(mm + 0, __ATOMIC_RELAXED, __HIP_MEMORY_SCOPE_AGENT));
        sres[1] = __uint_as_float(
            __hip_atomic_load(mm + 1, __ATOMIC_RELAXED, __HIP_MEMORY_SCOPE_AGENT));
    }
    __syncthreads();
    out[n] = sres[1] + sres[0] - v;
}

extern "C" void kernel_launch(void* const* d_in, const int* in_sizes, int n_in,
                              void* d_out, int out_size, void* d_ws, size_t ws_size,
                              hipStream_t stream) {
    const float* samples = (const float*)d_in[0];
    const float* means   = (const float*)d_in[1];
    const float* stds    = (const float*)d_in[2];
    unsigned char* ws = (unsigned char*)d_ws;
    float* out = (float*)d_out;

    kde_fused<<<dim3(NS / (NT * 16 * 4), MSPLIT), 256, 0, stream>>>(samples, means,
                                                                    stds, ws);
    reduce_flip<<<dim3(RBLK), 256, 0, stream>>>(ws, out);
}

// Round 24
// 16.840 us; speedup vs baseline: 1.0336x; 1.0336x over previous
//
#include <hip/hip_runtime.h>

#define NS 8192
#define MS 2048
#define DD 32
#define MSPLIT 16
#define MCH 128       // m per block
#define NITS 8        // m-tiles per block
#define RBLK 32       // reduce blocks

typedef __attribute__((ext_vector_type(8))) short bf16x8;
typedef __attribute__((ext_vector_type(4))) float f32x4;
typedef unsigned short u16;
typedef unsigned int u32;

// ws byte offsets
#define PART_OFF 0                          // [MSPLIT][NS] f32 (512 KB)
#define MM_OFF   (MSPLIT * NS * 4)          // 2 u32 (min,max bits)
#define CNT_OFF  (MM_OFF + 8)               // 1 u32

__device__ inline float fast_exp2(float x) {
#if __has_builtin(__builtin_amdgcn_exp2f)
    return __builtin_amdgcn_exp2f(x);
#else
    return exp2f(x);
#endif
}
__device__ inline float fast_rcp(float x) {
#if __has_builtin(__builtin_amdgcn_rcpf)
    return __builtin_amdgcn_rcpf(x);
#else
    return 1.0f / x;
#endif
}

__device__ inline u32 cvt_pk_bf16(float a, float b) {
    u32 r;
    asm("v_cvt_pk_bf16_f32 %0, %1, %2" : "=v"(r) : "v"(a), "v"(b));
    return r;
}

// hi-only pack (W: lo term dropped — error budget 2.2e-8 vs 4.5e-8 threshold)
__device__ inline bf16x8 pack8(const float* v) {
    union { u32 u[4]; bf16x8 b; } H;
#pragma unroll
    for (int j = 0; j < 4; ++j) H.u[j] = cvt_pk_bf16(v[2 * j], v[2 * j + 1]);
    return H.b;
}

// Split 8 floats into hi/lo bf16x8 (RNE) — used for X.
__device__ inline void split8(const float* v, bf16x8& hi, bf16x8& lo) {
    union { u32 u[4]; bf16x8 b; } H, L;
#pragma unroll
    for (int j = 0; j < 4; ++j) {
        u32 h = cvt_pk_bf16(v[2 * j], v[2 * j + 1]);
        float ha = __uint_as_float(h << 16);
        float hb = __uint_as_float(h & 0xFFFF0000u);
        L.u[j] = cvt_pk_bf16(v[2 * j] - ha, v[2 * j + 1] - hb);
        H.u[j] = h;
    }
    hi = H.b;
    lo = L.b;
}

// FINAL (R22 config, 16.85us): W->LDS hi-only conversion in fragment order,
// X hi/lo split in-register, D = W·X (m on rows), 4 MFMAs + 16 exp per tile,
// 2-shfl m-reduce, coalesced partial write. MSPLIT=16 balances conversion
// redundancy vs occupancy (measured optimum: 32 and 8 both worse).
__global__ __launch_bounds__(256, 4) void kde_fused(const float* __restrict__ samples,
                                                    const float* __restrict__ means,
                                                    const float* __restrict__ stds,
                                                    unsigned char* __restrict__ wsb) {
    __shared__ u16 WBH[NITS * 512], WCH[NITS * 512];   // [it][qd][r15][8]
    __shared__ float A2s[MCH];

    const int t = threadIdx.x;
    const int m0 = blockIdx.y * MCH;
    const float L2E = 1.4426950408889634f;

    if (blockIdx.x == 0 && blockIdx.y == 0 && t == 0) {
        unsigned* mm = (unsigned*)(wsb + MM_OFF);
        mm[0] = 0x7f7fffffu;  // FLT_MAX bits (uint cmp == float cmp, all positive)
        mm[1] = 0u;
        *(unsigned*)(wsb + CNT_OFF) = 0u;
    }

    // ---- phase 1: W chunk -> LDS (hi only), one thread per (m_local, 16-d half) ----
    {
        const int ml = t >> 1, half = t & 1, d0 = half * 16;
        const float* mp = means + (size_t)(m0 + ml) * DD + d0;
        const float* vp = stds  + (size_t)(m0 + ml) * DD + d0;
        float mu[16], sd[16];
#pragma unroll
        for (int j = 0; j < 4; ++j) {
            float4 a4 = *(const float4*)(mp + j * 4);
            float4 c4 = *(const float4*)(vp + j * 4);
            mu[j*4+0]=a4.x; mu[j*4+1]=a4.y; mu[j*4+2]=a4.z; mu[j*4+3]=a4.w;
            sd[j*4+0]=c4.x; sd[j*4+1]=c4.y; sd[j*4+2]=c4.z; sd[j*4+3]=c4.w;
        }
        float Bv[16], Cv[16], a = 0.f;
#pragma unroll
        for (int j = 0; j < 16; ++j) {
            float inv = fast_rcp(sd[j]);
            Bv[j] = L2E * mu[j] * inv;
            Cv[j] = -0.5f * L2E * inv;
            a += mu[j] * mu[j] * inv;
        }
        a += __shfl_xor(a, 1);   // combine the two 16-d halves of row ml
        if (half == 0) A2s[ml] = -0.5f * L2E * a - 11.0f;  // -log2(M) folds mean

        const int it = ml >> 4, r15 = ml & 15;
#pragma unroll
        for (int r2 = 0; r2 < 2; ++r2) {
            const int qd = half * 2 + r2;
            const int base = ((it * 4 + qd) * 16 + r15) * 8;
            *(bf16x8*)&WBH[base] = pack8(Bv + r2 * 8);
            *(bf16x8*)&WCH[base] = pack8(Cv + r2 * 8);
        }
    }

    // ---- phase 2: X fragments straight from samples (all 4 tiles up front) ----
    const int lane = t & 63, wid = t >> 6;
    const int r15 = lane & 15, g = lane >> 4;
    const int n0 = blockIdx.x * 256 + wid * 64;

    bf16x8 xh[4], xl[4], qh[4], ql[4];
#pragma unroll
    for (int nt = 0; nt < 4; ++nt) {
        const float* sp = samples + (size_t)(n0 + nt * 16 + r15) * DD + g * 8;
        float4 a4 = *(const float4*)sp, b4 = *(const float4*)(sp + 4);
        float xv[8] = {a4.x, a4.y, a4.z, a4.w, b4.x, b4.y, b4.z, b4.w};
        float qv[8];
#pragma unroll
        for (int j = 0; j < 8; ++j) qv[j] = xv[j] * xv[j];
        split8(xv, xh[nt], xl[nt]);
        split8(qv, qh[nt], ql[nt]);
    }

    __syncthreads();

    // ---- phase 3: m-loop, D = W·X (m on rows), 4 MFMAs per tile ----
    float rs[4] = {0.f, 0.f, 0.f, 0.f};

#pragma unroll 2
    for (int it = 0; it < NITS; ++it) {
        const int base = ((it * 4 + g) * 16 + r15) * 8;
        bf16x8 bh = *(const bf16x8*)&WBH[base];
        bf16x8 ch = *(const bf16x8*)&WCH[base];
        // rows of this lane are m = it*16 + g*4 + r  ->  16B-aligned f32x4
        const f32x4 a2v = *(const f32x4*)&A2s[it * 16 + g * 4];
#pragma unroll
        for (int nt = 0; nt < 4; ++nt) {
            f32x4 acc = a2v;
            acc = __builtin_amdgcn_mfma_f32_16x16x32_bf16(bh, xh[nt], acc, 0, 0, 0);
            acc = __builtin_amdgcn_mfma_f32_16x16x32_bf16(ch, qh[nt], acc, 0, 0, 0);
            acc = __builtin_amdgcn_mfma_f32_16x16x32_bf16(bh, xl[nt], acc, 0, 0, 0);
            acc = __builtin_amdgcn_mfma_f32_16x16x32_bf16(ch, ql[nt], acc, 0, 0, 0);
            rs[nt] += (fast_exp2(acc[0]) + fast_exp2(acc[1]))
                    + (fast_exp2(acc[2]) + fast_exp2(acc[3]));
        }
    }

    // sum the 4 g-groups (m-row blocks): 2 shfl steps
#pragma unroll
    for (int nt = 0; nt < 4; ++nt) {
        rs[nt] += __shfl_xor(rs[nt], 16);
        rs[nt] += __shfl_xor(rs[nt], 32);
    }

    float* partial = (float*)(wsb + PART_OFF);
    if (g == 0) {   // lanes 0..15: n = n0 + nt*16 + r15, 64B coalesced per nt
#pragma unroll
        for (int nt = 0; nt < 4; ++nt)
            partial[(size_t)blockIdx.y * NS + n0 + nt * 16 + r15] = rs[nt];
    }
}

// Merged reduce+flip (R16, proven): 32 co-resident blocks; dist in registers;
// min/max atomics; counter rendezvous (cnt initialized by kde_fused, ordered
// by the kernel boundary); distributed flip.
__global__ __launch_bounds__(256) void reduce_flip(unsigned char* __restrict__ wsb,
                                                   float* __restrict__ out) {
    const float* partial = (const float*)(wsb + PART_OFF);
    unsigned* mm = (unsigned*)(wsb + MM_OFF);
    unsigned* cnt = (unsigned*)(wsb + CNT_OFF);

    const int tid = threadIdx.x;
    const int n = blockIdx.x * 256 + tid;
    float v = 0.f;
#pragma unroll
    for (int j = 0; j < MSPLIT; ++j) v += partial[(size_t)j * NS + n];

    float mn = v, mx = v;
#pragma unroll
    for (int o = 1; o < 64; o <<= 1) {
        mn = fminf(mn, __shfl_xor(mn, o));
        mx = fmaxf(mx, __shfl_xor(mx, o));
    }
    __shared__ float smn[4], smx[4];
    __shared__ float sres[2];
    const int wv = tid >> 6, ln = tid & 63;
    if (ln == 0) { smn[wv] = mn; smx[wv] = mx; }
    __syncthreads();
    if (tid == 0) {
#pragma unroll
        for (int j = 1; j < 4; ++j) {
            mn = fminf(mn, smn[j]);
            mx = fmaxf(mx, smx[j]);
        }
        atomicMin(mm + 0, __float_as_uint(mn));
        atomicMax(mm + 1, __float_as_uint(mx));
        __threadfence();                       // release our atomics
        atomicAdd(cnt, 1u);
        while (__hip_atomic_load(cnt, __ATOMIC_ACQUIRE, __HIP_MEMORY_SCOPE_AGENT)
               < RBLK) {}
        sres[0] = __uint_as_float(
            __hip_atomic_load(mm + 0, __ATOMIC_RELAXED, __HIP_MEMORY_SCOPE_AGENT));
        sres[1] = __uint_as_float(
            __hip_atomic_load(mm + 1, __ATOMIC_RELAXED, __HIP_MEMORY_SCOPE_AGENT));
    }
    __syncthreads();
    out[n] = sres[1] + sres[0] - v;
}

extern "C" void kernel_launch(void* const* d_in, const int* in_sizes, int n_in,
                              void* d_out, int out_size, void* d_ws, size_t ws_size,
                              hipStream_t stream) {
    const float* samples = (const float*)d_in[0];
    const float* means   = (const float*)d_in[1];
    const float* stds    = (const float*)d_in[2];
    unsigned char* ws = (unsigned char*)d_ws;
    float* out = (float*)d_out;

    kde_fused<<<dim3(NS / 256, MSPLIT), 256, 0, stream>>>(samples, means, stds, ws);
    reduce_flip<<<dim3(RBLK), 256, 0, stream>>>(ws, out);
}